// Round 1
// baseline (2957.064 us; speedup 1.0000x reference)
//
#include <hip/hip_runtime.h>

#define BN 4
#define CC 256
#define NN 4096
#define C2 64
#define CR 32
#define OCH 128

// ---------------------------------------------------------------------------
// out[b][c][n] = bias[c] + sum_j W[c][j] * x[b][j][n]   (M=256,N=4096,K=256)
__global__ __launch_bounds__(256) void k_proj(const float* __restrict__ x,
    const float* __restrict__ W, const float* __restrict__ bias,
    float* __restrict__ out) {
  __shared__ float a_s[64][65];
  __shared__ float b_s[64][64];
  const int b = blockIdx.z, c0 = blockIdx.y * 64, n0 = blockIdx.x * 64;
  const int t = threadIdx.x;
  const int ti4 = (t >> 4) << 2, tj4 = (t & 15) << 2;
  float acc[4][4] = {};
  const float* xb = x + (size_t)b * CC * NN;
  for (int k0 = 0; k0 < CC; k0 += 64) {
    __syncthreads();
    for (int idx = t; idx < 4096; idx += 256) {
      int i = idx >> 6, k = idx & 63;
      a_s[i][k] = W[(c0 + i) * CC + k0 + k];
    }
    for (int idx = t; idx < 4096; idx += 256) {
      int k = idx >> 6, j = idx & 63;
      b_s[k][j] = xb[(size_t)(k0 + k) * NN + n0 + j];
    }
    __syncthreads();
#pragma unroll 8
    for (int kk = 0; kk < 64; ++kk) {
      const float a0 = a_s[ti4 + 0][kk], a1 = a_s[ti4 + 1][kk];
      const float a2 = a_s[ti4 + 2][kk], a3 = a_s[ti4 + 3][kk];
      const float4 b4 = *(const float4*)&b_s[kk][tj4];
      acc[0][0] += a0 * b4.x; acc[0][1] += a0 * b4.y; acc[0][2] += a0 * b4.z; acc[0][3] += a0 * b4.w;
      acc[1][0] += a1 * b4.x; acc[1][1] += a1 * b4.y; acc[1][2] += a1 * b4.z; acc[1][3] += a1 * b4.w;
      acc[2][0] += a2 * b4.x; acc[2][1] += a2 * b4.y; acc[2][2] += a2 * b4.z; acc[2][3] += a2 * b4.w;
      acc[3][0] += a3 * b4.x; acc[3][1] += a3 * b4.y; acc[3][2] += a3 * b4.z; acc[3][3] += a3 * b4.w;
    }
  }
#pragma unroll
  for (int i = 0; i < 4; ++i) {
    const int c = c0 + ti4 + i;
    const float bv = bias[c];
    float4 o4;
    o4.x = acc[i][0] + bv; o4.y = acc[i][1] + bv;
    o4.z = acc[i][2] + bv; o4.w = acc[i][3] + bv;
    *(float4*)&out[((size_t)b * CC + c) * NN + n0 + tj4] = o4;
  }
}

// ---------------------------------------------------------------------------
// grouped conv1d: q2[b][o][n] = b1[o] + sum_{i<8,t<3} w1[o*24+i*3+t]*q1[b][o*8+i][n+t-1]
__global__ __launch_bounds__(256) void k_adj1(const float* __restrict__ q1,
    const float* __restrict__ w1, const float* __restrict__ b1,
    float* __restrict__ q2) {
  const int gid = blockIdx.x * 256 + threadIdx.x;  // B*32*N
  const int n = gid & (NN - 1);
  const int o = (gid >> 12) & 31;
  const int b = gid >> 17;
  const float* base = q1 + ((size_t)b * CC + o * 8) * NN;
  float s = b1[o];
#pragma unroll
  for (int i = 0; i < 8; ++i) {
    const float* r = base + (size_t)i * NN;
    const float wa = w1[o * 24 + i * 3 + 0];
    const float wb = w1[o * 24 + i * 3 + 1];
    const float wc = w1[o * 24 + i * 3 + 2];
    if (n > 0) s += wa * r[n - 1];
    s += wb * r[n];
    if (n < NN - 1) s += wc * r[n + 1];
  }
  q2[((size_t)b * CR + o) * NN + n] = s;
}

// ---------------------------------------------------------------------------
// conv1d: q3[b][k][n] = b2[k] + sum_{o<32,t<3} w2[k*96+o*3+t]*q2[b][o][n+t-1]
__global__ __launch_bounds__(256) void k_adj2(const float* __restrict__ q2,
    const float* __restrict__ w2, const float* __restrict__ b2,
    float* __restrict__ q3) {
  __shared__ float q2s[CR][258];
  __shared__ float wss[CR][3];
  const int b = blockIdx.z, k = blockIdx.y, n0 = blockIdx.x * 256;
  const int t = threadIdx.x;
  for (int idx = t; idx < CR * 258; idx += 256) {
    int c = idx / 258, nn = idx % 258;
    int n = n0 + nn - 1;
    q2s[c][nn] = (n >= 0 && n < NN) ? q2[((size_t)b * CR + c) * NN + n] : 0.f;
  }
  if (t < CR * 3) wss[t / 3][t % 3] = w2[k * 96 + t];
  __syncthreads();
  float s = b2[k];
#pragma unroll 8
  for (int c = 0; c < CR; ++c)
    s += wss[c][0] * q2s[c][t] + wss[c][1] * q2s[c][t + 1] + wss[c][2] * q2s[c][t + 2];
  q3[((size_t)b * C2 + k) * NN + n0 + t] = s;
}

// ---------------------------------------------------------------------------
// spatial mean of x per batch: two-stage deterministic reduction
__global__ __launch_bounds__(256) void k_spatial1(const float* __restrict__ x,
                                                  float* __restrict__ part) {
  const int b = blockIdx.y;
  const size_t off = (size_t)b * CC * NN + (size_t)blockIdx.x * 16384;
  float s = 0.f;
  for (int i = threadIdx.x; i < 16384; i += 256) s += x[off + i];
  __shared__ float red[256];
  red[threadIdx.x] = s;
  __syncthreads();
  for (int d = 128; d > 0; d >>= 1) {
    if (threadIdx.x < d) red[threadIdx.x] += red[threadIdx.x + d];
    __syncthreads();
  }
  if (threadIdx.x == 0) part[b * 64 + blockIdx.x] = red[0];
}

__global__ void k_spatial2(const float* __restrict__ part, float* __restrict__ spatial) {
  const int t = threadIdx.x;  // 256
  const int b = t >> 6, i = t & 63;
  float s = part[b * 64 + i];
  for (int d = 32; d > 0; d >>= 1) s += __shfl_down(s, d, 64);
  if (i == 0) spatial[b] = s * (1.0f / ((float)CC * NN));
}

// ---------------------------------------------------------------------------
// per-(b,m) online max / sum-exp over an n-segment of attn[b,n,m]
__global__ __launch_bounds__(256) void k_colstat(const float* __restrict__ q3,
    float* __restrict__ pmax, float* __restrict__ psum) {
  __shared__ float Qs[CR][64];
  const int b = blockIdx.z, seg = blockIdx.y;
  const int m = blockIdx.x * 256 + threadIdx.x;
  const float* q3b = q3 + (size_t)b * C2 * NN;
  float kv[CR];
#pragma unroll
  for (int c = 0; c < CR; ++c) kv[c] = q3b[(size_t)(2 * c + 1) * NN + m];
  float mx = -1e30f, sum = 0.f;
  const int nbeg = seg * 512;
  for (int n0 = nbeg; n0 < nbeg + 512; n0 += 64) {
    __syncthreads();
    for (int idx = threadIdx.x; idx < CR * 64; idx += 256)
      Qs[idx >> 6][idx & 63] = q3b[(size_t)((idx >> 6) * 2) * NN + n0 + (idx & 63)];
    __syncthreads();
#pragma unroll 4
    for (int nn = 0; nn < 64; ++nn) {
      float s = 0.f;
#pragma unroll
      for (int c = 0; c < CR; ++c) s += Qs[c][nn] * kv[c];
      if (s <= mx) {
        sum += __expf(s - mx);
      } else {
        sum = sum * __expf(mx - s) + 1.f;
        mx = s;
      }
    }
  }
  pmax[((size_t)b * 8 + seg) * NN + m] = mx;
  psum[((size_t)b * 8 + seg) * NN + m] = sum;
}

__global__ void k_colcomb(const float* __restrict__ pmax, const float* __restrict__ psum,
                          float* __restrict__ colmax, float* __restrict__ colsum) {
  const int gid = blockIdx.x * 256 + threadIdx.x;  // B*N = 16384
  const int b = gid >> 12, m = gid & (NN - 1);
  float M = -1e30f;
#pragma unroll
  for (int s = 0; s < 8; ++s) M = fmaxf(M, pmax[((size_t)b * 8 + s) * NN + m]);
  float S = 0.f;
#pragma unroll
  for (int s = 0; s < 8; ++s)
    S += psum[((size_t)b * 8 + s) * NN + m] * __expf(pmax[((size_t)b * 8 + s) * NN + m] - M);
  colmax[gid] = M;
  colsum[gid] = S;
}

// ---------------------------------------------------------------------------
// main fused kernel: per (b, 64-n tile), loop m chunks of 32:
//   recompute attn tile for all 4 batches, double softmax -> A, fusion += V*A^T
//   epilogue: fus = gamma*spatial[b]*fusion + x
__global__ __launch_bounds__(512) void k_main(const float* __restrict__ q3,
    const float* __restrict__ val, const float* __restrict__ x,
    const float* __restrict__ colmax, const float* __restrict__ colsum,
    const float* __restrict__ gamma, const float* __restrict__ spatial,
    float* __restrict__ fus) {
  __shared__ float Qs[BN][CR][64];   // 32 KB
  __shared__ float Ks[BN][CR][32];   // 16 KB
  __shared__ float Vs[CC][33];       // 33.8 KB (pad: conflict-free read)
  __shared__ float Ss[BN][64][32];   // 32 KB  raw attn tile
  __shared__ float As[32][68];       // 8.7 KB A^T tile ([m][n], 16B-mult stride)
  const int b = blockIdx.y, n0 = blockIdx.x * 64;
  const int t = threadIdx.x;
  for (int idx = t; idx < BN * CR * 64; idx += 512) {
    int bb = idx >> 11, c = (idx >> 6) & 31, nn = idx & 63;
    Qs[bb][c][nn] = q3[((size_t)bb * C2 + 2 * c) * NN + n0 + nn];
  }
  float acc[32];
#pragma unroll
  for (int i = 0; i < 32; ++i) acc[i] = 0.f;
  const int cth = t & 255, nh = t >> 8;     // accum role: channel + n-half
  const int bb_s = t >> 7, l_s = t & 127;   // S-compute role
  const int snn0 = (l_s >> 3) << 2;         // 0..60
  const int smm0 = (l_s & 7) << 2;          // 0..28
  const float* vb = val + (size_t)b * CC * NN;

  for (int m0 = 0; m0 < NN; m0 += 32) {
    __syncthreads();
    for (int idx = t; idx < BN * CR * 32; idx += 512) {
      int bb = idx >> 10, c = (idx >> 5) & 31, mm = idx & 31;
      Ks[bb][c][mm] = q3[((size_t)bb * C2 + 2 * c + 1) * NN + m0 + mm];
    }
    for (int idx = t; idx < CC * 32; idx += 512) {
      int c = idx >> 5, mm = idx & 31;
      Vs[c][mm] = vb[(size_t)c * NN + m0 + mm];
    }
    __syncthreads();
    // ---- attn tile (4 batches), register-blocked 4x4 per thread
    {
      float s[4][4] = {};
#pragma unroll 8
      for (int c = 0; c < CR; ++c) {
        const float4 k4 = *(const float4*)&Ks[bb_s][c][smm0];
        const float4 q4 = *(const float4*)&Qs[bb_s][c][snn0];
        s[0][0] += q4.x * k4.x; s[0][1] += q4.x * k4.y; s[0][2] += q4.x * k4.z; s[0][3] += q4.x * k4.w;
        s[1][0] += q4.y * k4.x; s[1][1] += q4.y * k4.y; s[1][2] += q4.y * k4.z; s[1][3] += q4.y * k4.w;
        s[2][0] += q4.z * k4.x; s[2][1] += q4.z * k4.y; s[2][2] += q4.z * k4.z; s[2][3] += q4.z * k4.w;
        s[3][0] += q4.w * k4.x; s[3][1] += q4.w * k4.y; s[3][2] += q4.w * k4.z; s[3][3] += q4.w * k4.w;
      }
#pragma unroll
      for (int r = 0; r < 4; ++r)
        *(float4*)&Ss[bb_s][snn0 + r][smm0] = make_float4(s[r][0], s[r][1], s[r][2], s[r][3]);
    }
    __syncthreads();
    // ---- double softmax -> A (A^T layout [m][n])
    for (int idx = t; idx < 2048; idx += 512) {
      int nn = idx >> 5, mm = idx & 31;
      const float s0 = Ss[0][nn][mm], s1 = Ss[1][nn][mm];
      const float s2 = Ss[2][nn][mm], s3 = Ss[3][nn][mm];
      const float mx = fmaxf(fmaxf(s0, s1), fmaxf(s2, s3));
      const float e0 = __expf(s0 - mx), e1 = __expf(s1 - mx);
      const float e2 = __expf(s2 - mx), e3 = __expf(s3 - mx);
      const float den = e0 + e1 + e2 + e3;
      const float sb = b == 0 ? s0 : (b == 1 ? s1 : (b == 2 ? s2 : s3));
      const float eb = b == 0 ? e0 : (b == 1 ? e1 : (b == 2 ? e2 : e3));
      const int mg = m0 + mm;
      const float af = eb / den;
      const float ab = __expf(sb - colmax[b * NN + mg]) / colsum[b * NN + mg];
      As[mm][nn] = af + ab;
    }
    __syncthreads();
    // ---- fusion accumulation: acc[n] += V[c][m] * A[m][n]
    {
      const float* vr = Vs[cth];
#pragma unroll 4
      for (int mm = 0; mm < 32; ++mm) {
        const float v = vr[mm];
        const float4* arow = (const float4*)&As[mm][nh * 32];
#pragma unroll
        for (int q = 0; q < 8; ++q) {
          const float4 a4 = arow[q];
          acc[q * 4 + 0] += v * a4.x; acc[q * 4 + 1] += v * a4.y;
          acc[q * 4 + 2] += v * a4.z; acc[q * 4 + 3] += v * a4.w;
        }
      }
    }
  }
  // ---- epilogue: fus = g*acc + x
  const float g = gamma[0] * spatial[b];
  const size_t base = ((size_t)b * CC + cth) * NN + n0 + nh * 32;
#pragma unroll
  for (int q = 0; q < 8; ++q) {
    const float4 xv = *(const float4*)&x[base + q * 4];
    float4 o;
    o.x = g * acc[q * 4 + 0] + xv.x;
    o.y = g * acc[q * 4 + 1] + xv.y;
    o.z = g * acc[q * 4 + 2] + xv.z;
    o.w = g * acc[q * 4 + 3] + xv.w;
    *(float4*)&fus[base + q * 4] = o;
  }
}

// ---------------------------------------------------------------------------
// weight transform for transposed conv: wp[p][i][tap][o],
// tap=(tyi,txi): ky=py+2*tyi, kx=px+2*txi; value = w_co[i][o][3-ky][3-kx]
__global__ void k_wprep(const float* __restrict__ w_co, float* __restrict__ wp) {
  const int gid = blockIdx.x * 256 + threadIdx.x;  // 4*256*4*128 = 524288
  const int o = gid & 127;
  const int tap = (gid >> 7) & 3;
  const int i = (gid >> 9) & 255;
  const int p = gid >> 17;
  const int py = p >> 1, px = p & 1;
  const int tyi = tap >> 1, txi = tap & 1;
  const int ky = py + 2 * tyi, kx = px + 2 * txi;
  wp[gid] = w_co[(i * 128 + o) * 16 + (3 - ky) * 4 + (3 - kx)];
}

// ---------------------------------------------------------------------------
// transposed conv (stride-2, k=4): per (b, parity, output row), all 128 oc
// out[b][o][2i'+py][2j'+px] = b_co[o] + sum_{i,tyi,txi} w * fus[b][i][i'-1+py+tyi][j'-1+px+txi]
__global__ __launch_bounds__(256) void k_deconv(const float* __restrict__ fus,
    const float* __restrict__ wp, const float* __restrict__ b_co,
    float* __restrict__ out) {
  __shared__ float f_s[16][2][66];
  __shared__ float w_s[16][4][128];
  const int iy_row = blockIdx.x;           // i' 0..63
  const int bp = blockIdx.y;               // b*4 + py*2 + px
  const int b = bp >> 2, py = (bp >> 1) & 1, px = bp & 1;
  const int t = threadIdx.x;
  const int o = t & 127, half = t >> 7;
  const int iy0 = iy_row - 1 + py;
  const int b0 = half * 32 + px;
  float acc[32];
#pragma unroll
  for (int q = 0; q < 32; ++q) acc[q] = 0.f;
  for (int ic0 = 0; ic0 < CC; ic0 += 16) {
    __syncthreads();
    for (int idx = t; idx < 16 * 2 * 66; idx += 256) {
      int ii = idx / 132, rem = idx % 132;
      int ry = rem / 66, col = rem % 66;
      int iy = iy0 + ry, ix = col - 1;
      float v = 0.f;
      if (iy >= 0 && iy < 64 && ix >= 0 && ix < 64)
        v = fus[((size_t)(b * CC + ic0 + ii)) * NN + iy * 64 + ix];
      f_s[ii][ry][col] = v;
    }
    {
      const float* wsrc = wp + (size_t)(bp & 3) * 131072 + (size_t)ic0 * 512;
      float* wdst = &w_s[0][0][0];
      for (int idx = t; idx < 8192; idx += 256) wdst[idx] = wsrc[idx];
    }
    __syncthreads();
#pragma unroll 2
    for (int ii = 0; ii < 16; ++ii) {
#pragma unroll
      for (int tyi = 0; tyi < 2; ++tyi) {
        const float w0 = w_s[ii][tyi * 2 + 0][o];
        const float w1 = w_s[ii][tyi * 2 + 1][o];
        const float* frow = &f_s[ii][tyi][0];
        float fp = frow[b0];
#pragma unroll 8
        for (int q = 0; q < 32; ++q) {
          const float fn = frow[b0 + q + 1];
          acc[q] += w0 * fp + w1 * fn;
          fp = fn;
        }
      }
    }
  }
  const int y = 2 * iy_row + py;
  const float bco = b_co[o];
  for (int q = 0; q < 32; ++q) {
    const int jj = half * 32 + q;
    out[(((size_t)b * OCH + o) * 128 + y) * 128 + 2 * jj + px] = acc[q] + bco;
  }
}

// ---------------------------------------------------------------------------
extern "C" void kernel_launch(void* const* d_in, const int* in_sizes, int n_in,
                              void* d_out, int out_size, void* d_ws, size_t ws_size,
                              hipStream_t stream) {
  const float* x     = (const float*)d_in[0];
  const float* wq    = (const float*)d_in[1];
  const float* bq    = (const float*)d_in[2];
  const float* wv    = (const float*)d_in[3];
  const float* bv    = (const float*)d_in[4];
  const float* w1    = (const float*)d_in[5];
  const float* b1    = (const float*)d_in[6];
  const float* w2    = (const float*)d_in[7];
  const float* b2    = (const float*)d_in[8];
  const float* gamma = (const float*)d_in[9];
  const float* w_co  = (const float*)d_in[10];
  const float* b_co  = (const float*)d_in[11];
  float* out = (float*)d_out;
  float* ws  = (float*)d_ws;

  float* fus     = ws;                    // 4*256*4096 (q1, later fusion)
  float* val     = fus + 4194304;         // 4*256*4096
  float* q2      = val + 4194304;         // 4*32*4096
  float* q3      = q2 + 524288;           // 4*64*4096
  float* colmax  = q3 + 1048576;          // 4*4096
  float* colsum  = colmax + 16384;        // 4*4096
  float* pmax    = colsum + 16384;        // 4*8*4096
  float* psum    = pmax + 131072;         // 4*8*4096
  float* part    = psum + 131072;         // 256
  float* spatial = part + 256;            // 4
  float* wp      = spatial + 4;           // 4*256*4*128
  (void)ws_size; (void)in_sizes; (void)n_in; (void)out_size;

  // q1 = wq@x + bq  (into fus buffer), val = wv@x + bv
  k_proj<<<dim3(64, 4, 4), 256, 0, stream>>>(x, wq, bq, fus);
  k_proj<<<dim3(64, 4, 4), 256, 0, stream>>>(x, wv, bv, val);
  // adjust convs -> q3 (query/key interleaved channels)
  k_adj1<<<dim3(2048), 256, 0, stream>>>(fus, w1, b1, q2);
  k_adj2<<<dim3(16, 64, 4), 256, 0, stream>>>(q2, w2, b2, q3);
  // batch means of x
  k_spatial1<<<dim3(64, 4), 256, 0, stream>>>(x, part);
  k_spatial2<<<dim3(1), 256, 0, stream>>>(part, spatial);
  // column stats for softmax over n
  k_colstat<<<dim3(16, 8, 4), 256, 0, stream>>>(q3, pmax, psum);
  k_colcomb<<<dim3(64), 256, 0, stream>>>(pmax, psum, colmax, colsum);
  // fused attn + double softmax + fusion GEMM + residual epilogue
  k_main<<<dim3(64, 4), 512, 0, stream>>>(q3, val, x, colmax, colsum, gamma, spatial, fus);
  // transposed conv
  k_wprep<<<dim3(2048), 256, 0, stream>>>(w_co, wp);
  k_deconv<<<dim3(64, 16), 256, 0, stream>>>(fus, wp, b_co, out);
}

// Round 2
// 1511.730 us; speedup vs baseline: 1.9561x; 1.9561x over previous
//
#include <hip/hip_runtime.h>

#define BN 4
#define CC 256
#define NN 4096
#define CR 32
#define OCH 128
#define SEGS 32

typedef float f32x4 __attribute__((ext_vector_type(4)));
typedef short short8 __attribute__((ext_vector_type(8)));
typedef unsigned short u16x8 __attribute__((ext_vector_type(8)));

__device__ __forceinline__ unsigned short f2b(float f) {
  unsigned u = __builtin_bit_cast(unsigned, f);
  u += 0x7fff + ((u >> 16) & 1);
  return (unsigned short)(u >> 16);
}
__device__ __forceinline__ float b2f(unsigned short h) {
  unsigned u = ((unsigned)h) << 16;
  return __builtin_bit_cast(float, u);
}

// ---------------------------------------------------------------------------
// f32 GEMM projection: out[b][c][n] = bias[c] + sum_j W[c][j] x[b][j][n]
__global__ __launch_bounds__(256) void k_proj(const float* __restrict__ x,
    const float* __restrict__ W, const float* __restrict__ bias,
    float* __restrict__ out) {
  __shared__ float a_s[64][65];
  __shared__ float b_s[64][64];
  const int b = blockIdx.z, c0 = blockIdx.y * 64, n0 = blockIdx.x * 64;
  const int t = threadIdx.x;
  const int ti4 = (t >> 4) << 2, tj4 = (t & 15) << 2;
  float acc[4][4] = {};
  const float* xb = x + (size_t)b * CC * NN;
  for (int k0 = 0; k0 < CC; k0 += 64) {
    __syncthreads();
    for (int idx = t; idx < 4096; idx += 256) {
      int i = idx >> 6, k = idx & 63;
      a_s[i][k] = W[(c0 + i) * CC + k0 + k];
    }
    for (int idx = t; idx < 4096; idx += 256) {
      int k = idx >> 6, j = idx & 63;
      b_s[k][j] = xb[(size_t)(k0 + k) * NN + n0 + j];
    }
    __syncthreads();
#pragma unroll 8
    for (int kk = 0; kk < 64; ++kk) {
      const float a0 = a_s[ti4 + 0][kk], a1 = a_s[ti4 + 1][kk];
      const float a2 = a_s[ti4 + 2][kk], a3 = a_s[ti4 + 3][kk];
      const float4 b4 = *(const float4*)&b_s[kk][tj4];
      acc[0][0] += a0 * b4.x; acc[0][1] += a0 * b4.y; acc[0][2] += a0 * b4.z; acc[0][3] += a0 * b4.w;
      acc[1][0] += a1 * b4.x; acc[1][1] += a1 * b4.y; acc[1][2] += a1 * b4.z; acc[1][3] += a1 * b4.w;
      acc[2][0] += a2 * b4.x; acc[2][1] += a2 * b4.y; acc[2][2] += a2 * b4.z; acc[2][3] += a2 * b4.w;
      acc[3][0] += a3 * b4.x; acc[3][1] += a3 * b4.y; acc[3][2] += a3 * b4.z; acc[3][3] += a3 * b4.w;
    }
  }
#pragma unroll
  for (int i = 0; i < 4; ++i) {
    const int c = c0 + ti4 + i;
    const float bv = bias[c];
    float4 o4;
    o4.x = acc[i][0] + bv; o4.y = acc[i][1] + bv;
    o4.z = acc[i][2] + bv; o4.w = acc[i][3] + bv;
    *(float4*)&out[((size_t)b * CC + c) * NN + n0 + tj4] = o4;
  }
}

// same GEMM, bf16 output (for V)
__global__ __launch_bounds__(256) void k_projb(const float* __restrict__ x,
    const float* __restrict__ W, const float* __restrict__ bias,
    unsigned short* __restrict__ out) {
  __shared__ float a_s[64][65];
  __shared__ float b_s[64][64];
  const int b = blockIdx.z, c0 = blockIdx.y * 64, n0 = blockIdx.x * 64;
  const int t = threadIdx.x;
  const int ti4 = (t >> 4) << 2, tj4 = (t & 15) << 2;
  float acc[4][4] = {};
  const float* xb = x + (size_t)b * CC * NN;
  for (int k0 = 0; k0 < CC; k0 += 64) {
    __syncthreads();
    for (int idx = t; idx < 4096; idx += 256) {
      int i = idx >> 6, k = idx & 63;
      a_s[i][k] = W[(c0 + i) * CC + k0 + k];
    }
    for (int idx = t; idx < 4096; idx += 256) {
      int k = idx >> 6, j = idx & 63;
      b_s[k][j] = xb[(size_t)(k0 + k) * NN + n0 + j];
    }
    __syncthreads();
#pragma unroll 8
    for (int kk = 0; kk < 64; ++kk) {
      const float a0 = a_s[ti4 + 0][kk], a1 = a_s[ti4 + 1][kk];
      const float a2 = a_s[ti4 + 2][kk], a3 = a_s[ti4 + 3][kk];
      const float4 b4 = *(const float4*)&b_s[kk][tj4];
      acc[0][0] += a0 * b4.x; acc[0][1] += a0 * b4.y; acc[0][2] += a0 * b4.z; acc[0][3] += a0 * b4.w;
      acc[1][0] += a1 * b4.x; acc[1][1] += a1 * b4.y; acc[1][2] += a1 * b4.z; acc[1][3] += a1 * b4.w;
      acc[2][0] += a2 * b4.x; acc[2][1] += a2 * b4.y; acc[2][2] += a2 * b4.z; acc[2][3] += a2 * b4.w;
      acc[3][0] += a3 * b4.x; acc[3][1] += a3 * b4.y; acc[3][2] += a3 * b4.z; acc[3][3] += a3 * b4.w;
    }
  }
#pragma unroll
  for (int i = 0; i < 4; ++i) {
    const int c = c0 + ti4 + i;
    const float bv = bias[c];
    ushort4 o4;
    o4.x = f2b(acc[i][0] + bv); o4.y = f2b(acc[i][1] + bv);
    o4.z = f2b(acc[i][2] + bv); o4.w = f2b(acc[i][3] + bv);
    *(ushort4*)&out[((size_t)b * CC + c) * NN + n0 + tj4] = o4;
  }
}

// ---------------------------------------------------------------------------
// grouped conv1d (f32)
__global__ __launch_bounds__(256) void k_adj1(const float* __restrict__ q1,
    const float* __restrict__ w1, const float* __restrict__ b1,
    float* __restrict__ q2) {
  const int gid = blockIdx.x * 256 + threadIdx.x;  // B*32*N
  const int n = gid & (NN - 1);
  const int o = (gid >> 12) & 31;
  const int b = gid >> 17;
  const float* base = q1 + ((size_t)b * CC + o * 8) * NN;
  float s = b1[o];
#pragma unroll
  for (int i = 0; i < 8; ++i) {
    const float* r = base + (size_t)i * NN;
    const float wa = w1[o * 24 + i * 3 + 0];
    const float wb = w1[o * 24 + i * 3 + 1];
    const float wc = w1[o * 24 + i * 3 + 2];
    if (n > 0) s += wa * r[n - 1];
    s += wb * r[n];
    if (n < NN - 1) s += wc * r[n + 1];
  }
  q2[((size_t)b * CR + o) * NN + n] = s;
}

// ---------------------------------------------------------------------------
// conv1d 32->64ch, writes bf16 TRANSPOSED Qt[b][n][32], Kt[b][n][32]
// (even output channels -> Qt, odd -> Kt)
__global__ __launch_bounds__(256) void k_adj2(const float* __restrict__ q2,
    const float* __restrict__ w2, const float* __restrict__ b2,
    unsigned short* __restrict__ Qt, unsigned short* __restrict__ Kt) {
  __shared__ float q2s[32][66];
  __shared__ float w2t[96][64];   // [c*3+tap][k]
  __shared__ float b2s[64];
  const int b = blockIdx.y, n0 = blockIdx.x * 64;
  const int t = threadIdx.x;
  for (int idx = t; idx < 32 * 66; idx += 256) {
    int c = idx / 66, nn = idx % 66;
    int n = n0 + nn - 1;
    q2s[c][nn] = (n >= 0 && n < NN) ? q2[((size_t)b * CR + c) * NN + n] : 0.f;
  }
  for (int idx = t; idx < 96 * 64; idx += 256) {
    int k = idx & 63, ct = idx >> 6;
    w2t[ct][k] = w2[k * 96 + ct];
  }
  if (t < 64) b2s[t] = b2[t];
  __syncthreads();
  const int nn = t & 63, kh = t >> 6;   // kh: 16-channel group 0..3
  float acc[16];
#pragma unroll
  for (int i = 0; i < 16; ++i) acc[i] = b2s[kh * 16 + i];
  for (int c = 0; c < 32; ++c) {
    const float x0 = q2s[c][nn], x1 = q2s[c][nn + 1], x2 = q2s[c][nn + 2];
    const float* wa = &w2t[c * 3 + 0][kh * 16];
    const float* wb = &w2t[c * 3 + 1][kh * 16];
    const float* wc = &w2t[c * 3 + 2][kh * 16];
#pragma unroll
    for (int i = 0; i < 16; ++i)
      acc[i] += wa[i] * x0 + wb[i] * x1 + wc[i] * x2;
  }
  const size_t row = ((size_t)b * NN + n0 + nn) * 32;
  u16x8 qo, ko;
#pragma unroll
  for (int i = 0; i < 8; ++i) {
    qo[i] = f2b(acc[2 * i]);
    ko[i] = f2b(acc[2 * i + 1]);
  }
  *(u16x8*)(Qt + row + kh * 8) = qo;
  *(u16x8*)(Kt + row + kh * 8) = ko;
}

// ---------------------------------------------------------------------------
// spatial mean of x per batch
__global__ __launch_bounds__(256) void k_spatial1(const float* __restrict__ x,
                                                  float* __restrict__ part) {
  const int b = blockIdx.y;
  const size_t off = (size_t)b * CC * NN + (size_t)blockIdx.x * 16384;
  float s = 0.f;
  for (int i = threadIdx.x; i < 16384; i += 256) s += x[off + i];
  __shared__ float red[256];
  red[threadIdx.x] = s;
  __syncthreads();
  for (int d = 128; d > 0; d >>= 1) {
    if (threadIdx.x < d) red[threadIdx.x] += red[threadIdx.x + d];
    __syncthreads();
  }
  if (threadIdx.x == 0) part[b * 64 + blockIdx.x] = red[0];
}

__global__ void k_spatial2(const float* __restrict__ part, float* __restrict__ spatial) {
  const int t = threadIdx.x;  // 256
  const int b = t >> 6, i = t & 63;
  float s = part[b * 64 + i];
  for (int d = 32; d > 0; d >>= 1) s += __shfl_down(s, d, 64);
  if (i == 0) spatial[b] = s * (1.0f / ((float)CC * NN));
}

// ---------------------------------------------------------------------------
// column exp-sum over an n-segment: psum[b][seg][m] = sum_n exp(S[b][n][m])
// (no max subtraction: logits bounded, clamped at 60 for safety)
__global__ __launch_bounds__(256) void k_colstat(const unsigned short* __restrict__ Qt,
    const unsigned short* __restrict__ Kt, float* __restrict__ psum) {
  __shared__ float Qsf[128][36];
  const int b = blockIdx.z, seg = blockIdx.y;
  const int t = threadIdx.x;
  const int m = blockIdx.x * 256 + t;
  {
    const int nn = t >> 1, half = t & 1;
    const unsigned short* src = Qt + ((size_t)(b * NN + seg * 128 + nn) * 32 + half * 16);
    u16x8 v0 = *(const u16x8*)src;
    u16x8 v1 = *(const u16x8*)(src + 8);
#pragma unroll
    for (int i = 0; i < 8; ++i) {
      Qsf[nn][half * 16 + i] = b2f(v0[i]);
      Qsf[nn][half * 16 + 8 + i] = b2f(v1[i]);
    }
  }
  float kv[32];
  {
    const unsigned short* src = Kt + (size_t)(b * NN + m) * 32;
#pragma unroll
    for (int q = 0; q < 4; ++q) {
      u16x8 v = *(const u16x8*)(src + q * 8);
#pragma unroll
      for (int i = 0; i < 8; ++i) kv[q * 8 + i] = b2f(v[i]);
    }
  }
  __syncthreads();
  float sum = 0.f;
  for (int nn = 0; nn < 128; ++nn) {
    float s = 0.f;
#pragma unroll
    for (int c = 0; c < 32; ++c) s += Qsf[nn][c] * kv[c];
    sum += __expf(fminf(s, 60.f));
  }
  psum[((size_t)(b * SEGS + seg)) * NN + m] = sum;
}

__global__ void k_rsum(const float* __restrict__ psum, float* __restrict__ rcs) {
  const int gid = blockIdx.x * 256 + threadIdx.x;  // B*N = 16384
  const int b = gid >> 12, m = gid & (NN - 1);
  float S = 0.f;
#pragma unroll
  for (int s = 0; s < SEGS; ++s) S += psum[((size_t)(b * SEGS + s)) * NN + m];
  rcs[gid] = 1.0f / S;
}

// ---------------------------------------------------------------------------
// MFMA main kernel. Per block (b, 64-n tile), loop m in 64-chunks:
//   S tiles for 4 batches via mfma_16x16x32_bf16 (K = 32 channels),
//   in-register double softmax, A -> swizzled LDS (bf16),
//   PV: fusion[c][n] += V[c][m] * A[n][m] via MFMA.
__global__ __launch_bounds__(512) void k_main(const unsigned short* __restrict__ Qt,
    const unsigned short* __restrict__ Kt, const unsigned short* __restrict__ Vb,
    const float* __restrict__ x, const float* __restrict__ rcs,
    const float* __restrict__ gamma, const float* __restrict__ spatial,
    float* __restrict__ fus) {
  __shared__ unsigned short As[64 * 64];   // swizzled [n][m] bf16, 8 KB
  const int b = blockIdx.y, n0 = blockIdx.x * 64;
  const int t = threadIdx.x;
  const int w = t >> 6, l = t & 63;
  const int lo = l & 15, hi = l >> 4;
  const int mt = w & 3, nt2 = w >> 2;      // S-phase tile assignment

  // Q fragments, kept in registers for the whole kernel: [pos][batch]
  short8 qf[2][4];
#pragma unroll
  for (int pos = 0; pos < 2; ++pos) {
    const int n = n0 + (nt2 * 2 + pos) * 16 + lo;
#pragma unroll
    for (int bb = 0; bb < 4; ++bb)
      qf[pos][bb] = *(const short8*)(Qt + ((size_t)(bb * NN + n) * 32 + hi * 8));
  }

  f32x4 acc[2][4];
#pragma unroll
  for (int ct = 0; ct < 2; ++ct)
#pragma unroll
    for (int nt = 0; nt < 4; ++nt) acc[ct][nt] = (f32x4){0.f, 0.f, 0.f, 0.f};

  const float* rcs_b = rcs + b * NN;
  const f32x4 zero4 = (f32x4){0.f, 0.f, 0.f, 0.f};

  for (int m0 = 0; m0 < NN; m0 += 64) {
    // ---- K fragments (direct global, L2-resident)
    const int mS = m0 + mt * 16 + lo;
    short8 kf[4];
#pragma unroll
    for (int bb = 0; bb < 4; ++bb)
      kf[bb] = *(const short8*)(Kt + ((size_t)(bb * NN + mS) * 32 + hi * 8));
    // ---- S tiles: s[pos][bb] covers (n = ntile*16 + hi*4 + r, m = mt*16 + lo)
    f32x4 s[2][4];
#pragma unroll
    for (int pos = 0; pos < 2; ++pos)
#pragma unroll
      for (int bb = 0; bb < 4; ++bb)
        s[pos][bb] = __builtin_amdgcn_mfma_f32_16x16x32_bf16(qf[pos][bb], kf[bb], zero4, 0, 0, 0);
    // ---- double softmax, in registers (no max-subtract; logits bounded)
    const float rcsm = rcs_b[mS];
    float av[2][4];
#pragma unroll
    for (int pos = 0; pos < 2; ++pos) {
#pragma unroll
      for (int r = 0; r < 4; ++r) {
        const float e0 = __expf(fminf(s[pos][0][r], 60.f));
        const float e1 = __expf(fminf(s[pos][1][r], 60.f));
        const float e2 = __expf(fminf(s[pos][2][r], 60.f));
        const float e3 = __expf(fminf(s[pos][3][r], 60.f));
        const float den = e0 + e1 + e2 + e3;
        const float eb = b == 0 ? e0 : (b == 1 ? e1 : (b == 2 ? e2 : e3));
        av[pos][r] = eb * (__builtin_amdgcn_rcpf(den) + rcsm);
      }
    }
    __syncthreads();   // previous chunk's PV reads of As complete
#pragma unroll
    for (int pos = 0; pos < 2; ++pos) {
      const int nl0 = (nt2 * 2 + pos) * 16 + hi * 4;
      const int ml = mt * 16 + lo;
#pragma unroll
      for (int r = 0; r < 4; ++r) {
        const int nl = nl0 + r;
        As[nl * 64 + (ml ^ ((nl & 7) << 3))] = f2b(av[pos][r]);
      }
    }
    __syncthreads();   // As ready
    // ---- PV accumulation: wave owns channels [w*32, w*32+32)
#pragma unroll
    for (int kt = 0; kt < 2; ++kt) {
      short8 vf[2];
#pragma unroll
      for (int ct = 0; ct < 2; ++ct) {
        const int c = w * 32 + ct * 16 + lo;
        vf[ct] = *(const short8*)(Vb + ((size_t)(b * CC + c) * NN + m0 + kt * 32 + hi * 8));
      }
#pragma unroll
      for (int nt = 0; nt < 4; ++nt) {
        const int nl = nt * 16 + lo;
        const short8 af = *(const short8*)(As + nl * 64 + (((kt * 4 + hi) ^ (nl & 7)) << 3));
        acc[0][nt] = __builtin_amdgcn_mfma_f32_16x16x32_bf16(vf[0], af, acc[0][nt], 0, 0, 0);
        acc[1][nt] = __builtin_amdgcn_mfma_f32_16x16x32_bf16(vf[1], af, acc[1][nt], 0, 0, 0);
      }
    }
  }
  // ---- epilogue: fus = gamma*spatial[b]*acc + x
  const float g = gamma[0] * spatial[b];
#pragma unroll
  for (int ct = 0; ct < 2; ++ct) {
#pragma unroll
    for (int nt = 0; nt < 4; ++nt) {
#pragma unroll
      for (int r = 0; r < 4; ++r) {
        const int c = w * 32 + ct * 16 + hi * 4 + r;
        const size_t off = ((size_t)(b * CC + c)) * NN + n0 + nt * 16 + lo;
        fus[off] = g * acc[ct][nt][r] + x[off];
      }
    }
  }
}

// ---------------------------------------------------------------------------
// weight transform for transposed conv: wp[p][i][tap][o]
__global__ void k_wprep(const float* __restrict__ w_co, float* __restrict__ wp) {
  const int gid = blockIdx.x * 256 + threadIdx.x;  // 4*256*4*128 = 524288
  const int o = gid & 127;
  const int tap = (gid >> 7) & 3;
  const int i = (gid >> 9) & 255;
  const int p = gid >> 17;
  const int py = p >> 1, px = p & 1;
  const int tyi = tap >> 1, txi = tap & 1;
  const int ky = py + 2 * tyi, kx = px + 2 * txi;
  wp[gid] = w_co[(i * 128 + o) * 16 + (3 - ky) * 4 + (3 - kx)];
}

// ---------------------------------------------------------------------------
// transposed conv (stride-2, k=4)
__global__ __launch_bounds__(256) void k_deconv(const float* __restrict__ fus,
    const float* __restrict__ wp, const float* __restrict__ b_co,
    float* __restrict__ out) {
  __shared__ float f_s[16][2][66];
  __shared__ float w_s[16][4][128];
  const int iy_row = blockIdx.x;           // i' 0..63
  const int bp = blockIdx.y;               // b*4 + py*2 + px
  const int b = bp >> 2, py = (bp >> 1) & 1, px = bp & 1;
  const int t = threadIdx.x;
  const int o = t & 127, half = t >> 7;
  const int iy0 = iy_row - 1 + py;
  const int b0 = half * 32 + px;
  float acc[32];
#pragma unroll
  for (int q = 0; q < 32; ++q) acc[q] = 0.f;
  for (int ic0 = 0; ic0 < CC; ic0 += 16) {
    __syncthreads();
    for (int idx = t; idx < 16 * 2 * 66; idx += 256) {
      int ii = idx / 132, rem = idx % 132;
      int ry = rem / 66, col = rem % 66;
      int iy = iy0 + ry, ix = col - 1;
      float v = 0.f;
      if (iy >= 0 && iy < 64 && ix >= 0 && ix < 64)
        v = fus[((size_t)(b * CC + ic0 + ii)) * NN + iy * 64 + ix];
      f_s[ii][ry][col] = v;
    }
    {
      const float* wsrc = wp + (size_t)(bp & 3) * 131072 + (size_t)ic0 * 512;
      float* wdst = &w_s[0][0][0];
      for (int idx = t; idx < 8192; idx += 256) wdst[idx] = wsrc[idx];
    }
    __syncthreads();
#pragma unroll 2
    for (int ii = 0; ii < 16; ++ii) {
#pragma unroll
      for (int tyi = 0; tyi < 2; ++tyi) {
        const float w0 = w_s[ii][tyi * 2 + 0][o];
        const float w1 = w_s[ii][tyi * 2 + 1][o];
        const float* frow = &f_s[ii][tyi][0];
        float fp = frow[b0];
#pragma unroll 8
        for (int q = 0; q < 32; ++q) {
          const float fn = frow[b0 + q + 1];
          acc[q] += w0 * fp + w1 * fn;
          fp = fn;
        }
      }
    }
  }
  const int y = 2 * iy_row + py;
  const float bco = b_co[o];
  for (int q = 0; q < 32; ++q) {
    const int jj = half * 32 + q;
    out[(((size_t)b * OCH + o) * 128 + y) * 128 + 2 * jj + px] = acc[q] + bco;
  }
}

// ---------------------------------------------------------------------------
extern "C" void kernel_launch(void* const* d_in, const int* in_sizes, int n_in,
                              void* d_out, int out_size, void* d_ws, size_t ws_size,
                              hipStream_t stream) {
  const float* x     = (const float*)d_in[0];
  const float* wq    = (const float*)d_in[1];
  const float* bq    = (const float*)d_in[2];
  const float* wv    = (const float*)d_in[3];
  const float* bv    = (const float*)d_in[4];
  const float* w1    = (const float*)d_in[5];
  const float* b1    = (const float*)d_in[6];
  const float* w2    = (const float*)d_in[7];
  const float* b2    = (const float*)d_in[8];
  const float* gamma = (const float*)d_in[9];
  const float* w_co  = (const float*)d_in[10];
  const float* b_co  = (const float*)d_in[11];
  float* out = (float*)d_out;

  char* p = (char*)d_ws;
  float*          fus     = (float*)p;          p += (size_t)4194304 * 4;
  unsigned short* Vb      = (unsigned short*)p; p += (size_t)4194304 * 2;
  float*          q2      = (float*)p;          p += (size_t)524288 * 4;
  unsigned short* Qt      = (unsigned short*)p; p += (size_t)524288 * 2;
  unsigned short* Kt      = (unsigned short*)p; p += (size_t)524288 * 2;
  float*          psum    = (float*)p;          p += (size_t)524288 * 4;
  float*          rcs     = (float*)p;          p += (size_t)16384 * 4;
  float*          part    = (float*)p;          p += (size_t)256 * 4;
  float*          spatial = (float*)p;          p += (size_t)4 * 4;
  float*          wp      = (float*)p;
  (void)ws_size; (void)in_sizes; (void)n_in; (void)out_size;

  // q1 = wq@x + bq (into fus buffer, f32); V = wv@x + bv (bf16)
  k_proj<<<dim3(64, 4, 4), 256, 0, stream>>>(x, wq, bq, fus);
  k_projb<<<dim3(64, 4, 4), 256, 0, stream>>>(x, wv, bv, Vb);
  // adjust convs -> transposed bf16 Q/K
  k_adj1<<<dim3(2048), 256, 0, stream>>>(fus, w1, b1, q2);
  k_adj2<<<dim3(64, 4), 256, 0, stream>>>(q2, w2, b2, Qt, Kt);
  // batch means of x
  k_spatial1<<<dim3(64, 4), 256, 0, stream>>>(x, part);
  k_spatial2<<<dim3(1), 256, 0, stream>>>(part, spatial);
  // column exp-sums for softmax over n
  k_colstat<<<dim3(16, SEGS, 4), 256, 0, stream>>>(Qt, Kt, psum);
  k_rsum<<<dim3(64), 256, 0, stream>>>(psum, rcs);
  // fused MFMA attn + double softmax + PV + residual epilogue
  k_main<<<dim3(64, 4), 512, 0, stream>>>(Qt, Kt, Vb, x, rcs, gamma, spatial, fus);
  // transposed conv
  k_wprep<<<dim3(2048), 256, 0, stream>>>(w_co, wp);
  k_deconv<<<dim3(64, 16), 256, 0, stream>>>(fus, wp, b_co, out);
}

// Round 3
// 457.961 us; speedup vs baseline: 6.4570x; 3.3010x over previous
//
#include <hip/hip_runtime.h>

#define BN 4
#define CC 256
#define NN 4096
#define CR 32
#define OCH 128
#define SEGS 32

typedef float f32x4 __attribute__((ext_vector_type(4)));
typedef short short8 __attribute__((ext_vector_type(8)));
typedef unsigned short u16x8 __attribute__((ext_vector_type(8)));
typedef unsigned short u16x4 __attribute__((ext_vector_type(4)));

__device__ __forceinline__ unsigned short f2b(float f) {
  unsigned u = __builtin_bit_cast(unsigned, f);
  u += 0x7fff + ((u >> 16) & 1);
  return (unsigned short)(u >> 16);
}
__device__ __forceinline__ float b2f(unsigned short h) {
  unsigned u = ((unsigned)h) << 16;
  return __builtin_bit_cast(float, u);
}

// ---------------------------------------------------------------------------
// f32 GEMM projection: out[b][c][n] = bias[c] + sum_j W[c][j] x[b][j][n]
__global__ __launch_bounds__(256) void k_proj(const float* __restrict__ x,
    const float* __restrict__ W, const float* __restrict__ bias,
    float* __restrict__ out) {
  __shared__ float a_s[64][65];
  __shared__ float b_s[64][64];
  const int b = blockIdx.z, c0 = blockIdx.y * 64, n0 = blockIdx.x * 64;
  const int t = threadIdx.x;
  const int ti4 = (t >> 4) << 2, tj4 = (t & 15) << 2;
  float acc[4][4] = {};
  const float* xb = x + (size_t)b * CC * NN;
  for (int k0 = 0; k0 < CC; k0 += 64) {
    __syncthreads();
    for (int idx = t; idx < 4096; idx += 256) {
      int i = idx >> 6, k = idx & 63;
      a_s[i][k] = W[(c0 + i) * CC + k0 + k];
    }
    for (int idx = t; idx < 4096; idx += 256) {
      int k = idx >> 6, j = idx & 63;
      b_s[k][j] = xb[(size_t)(k0 + k) * NN + n0 + j];
    }
    __syncthreads();
#pragma unroll 8
    for (int kk = 0; kk < 64; ++kk) {
      const float a0 = a_s[ti4 + 0][kk], a1 = a_s[ti4 + 1][kk];
      const float a2 = a_s[ti4 + 2][kk], a3 = a_s[ti4 + 3][kk];
      const float4 b4 = *(const float4*)&b_s[kk][tj4];
      acc[0][0] += a0 * b4.x; acc[0][1] += a0 * b4.y; acc[0][2] += a0 * b4.z; acc[0][3] += a0 * b4.w;
      acc[1][0] += a1 * b4.x; acc[1][1] += a1 * b4.y; acc[1][2] += a1 * b4.z; acc[1][3] += a1 * b4.w;
      acc[2][0] += a2 * b4.x; acc[2][1] += a2 * b4.y; acc[2][2] += a2 * b4.z; acc[2][3] += a2 * b4.w;
      acc[3][0] += a3 * b4.x; acc[3][1] += a3 * b4.y; acc[3][2] += a3 * b4.z; acc[3][3] += a3 * b4.w;
    }
  }
#pragma unroll
  for (int i = 0; i < 4; ++i) {
    const int c = c0 + ti4 + i;
    const float bv = bias[c];
    float4 o4;
    o4.x = acc[i][0] + bv; o4.y = acc[i][1] + bv;
    o4.z = acc[i][2] + bv; o4.w = acc[i][3] + bv;
    *(float4*)&out[((size_t)b * CC + c) * NN + n0 + tj4] = o4;
  }
}

// same GEMM, bf16 output (for V)
__global__ __launch_bounds__(256) void k_projb(const float* __restrict__ x,
    const float* __restrict__ W, const float* __restrict__ bias,
    unsigned short* __restrict__ out) {
  __shared__ float a_s[64][65];
  __shared__ float b_s[64][64];
  const int b = blockIdx.z, c0 = blockIdx.y * 64, n0 = blockIdx.x * 64;
  const int t = threadIdx.x;
  const int ti4 = (t >> 4) << 2, tj4 = (t & 15) << 2;
  float acc[4][4] = {};
  const float* xb = x + (size_t)b * CC * NN;
  for (int k0 = 0; k0 < CC; k0 += 64) {
    __syncthreads();
    for (int idx = t; idx < 4096; idx += 256) {
      int i = idx >> 6, k = idx & 63;
      a_s[i][k] = W[(c0 + i) * CC + k0 + k];
    }
    for (int idx = t; idx < 4096; idx += 256) {
      int k = idx >> 6, j = idx & 63;
      b_s[k][j] = xb[(size_t)(k0 + k) * NN + n0 + j];
    }
    __syncthreads();
#pragma unroll 8
    for (int kk = 0; kk < 64; ++kk) {
      const float a0 = a_s[ti4 + 0][kk], a1 = a_s[ti4 + 1][kk];
      const float a2 = a_s[ti4 + 2][kk], a3 = a_s[ti4 + 3][kk];
      const float4 b4 = *(const float4*)&b_s[kk][tj4];
      acc[0][0] += a0 * b4.x; acc[0][1] += a0 * b4.y; acc[0][2] += a0 * b4.z; acc[0][3] += a0 * b4.w;
      acc[1][0] += a1 * b4.x; acc[1][1] += a1 * b4.y; acc[1][2] += a1 * b4.z; acc[1][3] += a1 * b4.w;
      acc[2][0] += a2 * b4.x; acc[2][1] += a2 * b4.y; acc[2][2] += a2 * b4.z; acc[2][3] += a2 * b4.w;
      acc[3][0] += a3 * b4.x; acc[3][1] += a3 * b4.y; acc[3][2] += a3 * b4.z; acc[3][3] += a3 * b4.w;
    }
  }
#pragma unroll
  for (int i = 0; i < 4; ++i) {
    const int c = c0 + ti4 + i;
    const float bv = bias[c];
    ushort4 o4;
    o4.x = f2b(acc[i][0] + bv); o4.y = f2b(acc[i][1] + bv);
    o4.z = f2b(acc[i][2] + bv); o4.w = f2b(acc[i][3] + bv);
    *(ushort4*)&out[((size_t)b * CC + c) * NN + n0 + tj4] = o4;
  }
}

// ---------------------------------------------------------------------------
// grouped conv1d (f32)
__global__ __launch_bounds__(256) void k_adj1(const float* __restrict__ q1,
    const float* __restrict__ w1, const float* __restrict__ b1,
    float* __restrict__ q2) {
  const int gid = blockIdx.x * 256 + threadIdx.x;  // B*32*N
  const int n = gid & (NN - 1);
  const int o = (gid >> 12) & 31;
  const int b = gid >> 17;
  const float* base = q1 + ((size_t)b * CC + o * 8) * NN;
  float s = b1[o];
#pragma unroll
  for (int i = 0; i < 8; ++i) {
    const float* r = base + (size_t)i * NN;
    const float wa = w1[o * 24 + i * 3 + 0];
    const float wb = w1[o * 24 + i * 3 + 1];
    const float wc = w1[o * 24 + i * 3 + 2];
    if (n > 0) s += wa * r[n - 1];
    s += wb * r[n];
    if (n < NN - 1) s += wc * r[n + 1];
  }
  q2[((size_t)b * CR + o) * NN + n] = s;
}

// ---------------------------------------------------------------------------
// conv1d 32->64ch, writes bf16 TRANSPOSED Qt[b][n][32], Kt[b][n][32]
__global__ __launch_bounds__(256) void k_adj2(const float* __restrict__ q2,
    const float* __restrict__ w2, const float* __restrict__ b2,
    unsigned short* __restrict__ Qt, unsigned short* __restrict__ Kt) {
  __shared__ float q2s[32][66];
  __shared__ float w2t[96][64];   // [c*3+tap][k]
  __shared__ float b2s[64];
  const int b = blockIdx.y, n0 = blockIdx.x * 64;
  const int t = threadIdx.x;
  for (int idx = t; idx < 32 * 66; idx += 256) {
    int c = idx / 66, nn = idx % 66;
    int n = n0 + nn - 1;
    q2s[c][nn] = (n >= 0 && n < NN) ? q2[((size_t)b * CR + c) * NN + n] : 0.f;
  }
  for (int idx = t; idx < 96 * 64; idx += 256) {
    int k = idx & 63, ct = idx >> 6;
    w2t[ct][k] = w2[k * 96 + ct];
  }
  if (t < 64) b2s[t] = b2[t];
  __syncthreads();
  const int nn = t & 63, kh = t >> 6;   // kh: 16-channel group 0..3
  float acc[16];
#pragma unroll
  for (int i = 0; i < 16; ++i) acc[i] = b2s[kh * 16 + i];
  for (int c = 0; c < 32; ++c) {
    const float x0 = q2s[c][nn], x1 = q2s[c][nn + 1], x2 = q2s[c][nn + 2];
    const float* wa = &w2t[c * 3 + 0][kh * 16];
    const float* wb = &w2t[c * 3 + 1][kh * 16];
    const float* wc = &w2t[c * 3 + 2][kh * 16];
#pragma unroll
    for (int i = 0; i < 16; ++i)
      acc[i] += wa[i] * x0 + wb[i] * x1 + wc[i] * x2;
  }
  const size_t row = ((size_t)b * NN + n0 + nn) * 32;
  u16x8 qo, ko;
#pragma unroll
  for (int i = 0; i < 8; ++i) {
    qo[i] = f2b(acc[2 * i]);
    ko[i] = f2b(acc[2 * i + 1]);
  }
  *(u16x8*)(Qt + row + kh * 8) = qo;
  *(u16x8*)(Kt + row + kh * 8) = ko;
}

// ---------------------------------------------------------------------------
// spatial mean of x per batch
__global__ __launch_bounds__(256) void k_spatial1(const float* __restrict__ x,
                                                  float* __restrict__ part) {
  const int b = blockIdx.y;
  const size_t off = (size_t)b * CC * NN + (size_t)blockIdx.x * 16384;
  float s = 0.f;
  for (int i = threadIdx.x; i < 16384; i += 256) s += x[off + i];
  __shared__ float red[256];
  red[threadIdx.x] = s;
  __syncthreads();
  for (int d = 128; d > 0; d >>= 1) {
    if (threadIdx.x < d) red[threadIdx.x] += red[threadIdx.x + d];
    __syncthreads();
  }
  if (threadIdx.x == 0) part[b * 64 + blockIdx.x] = red[0];
}

__global__ void k_spatial2(const float* __restrict__ part, float* __restrict__ spatial) {
  const int t = threadIdx.x;  // 256
  const int b = t >> 6, i = t & 63;
  float s = part[b * 64 + i];
  for (int d = 32; d > 0; d >>= 1) s += __shfl_down(s, d, 64);
  if (i == 0) spatial[b] = s * (1.0f / ((float)CC * NN));
}

// ---------------------------------------------------------------------------
// column exp-sum over an n-segment: psum[b][seg][m] = sum_n exp(S[b][n][m])
__global__ __launch_bounds__(256) void k_colstat(const unsigned short* __restrict__ Qt,
    const unsigned short* __restrict__ Kt, float* __restrict__ psum) {
  __shared__ float Qsf[128][36];
  const int b = blockIdx.z, seg = blockIdx.y;
  const int t = threadIdx.x;
  const int m = blockIdx.x * 256 + t;
  {
    const int nn = t >> 1, half = t & 1;
    const unsigned short* src = Qt + ((size_t)(b * NN + seg * 128 + nn) * 32 + half * 16);
    u16x8 v0 = *(const u16x8*)src;
    u16x8 v1 = *(const u16x8*)(src + 8);
#pragma unroll
    for (int i = 0; i < 8; ++i) {
      Qsf[nn][half * 16 + i] = b2f(v0[i]);
      Qsf[nn][half * 16 + 8 + i] = b2f(v1[i]);
    }
  }
  float kv[32];
  {
    const unsigned short* src = Kt + (size_t)(b * NN + m) * 32;
#pragma unroll
    for (int q = 0; q < 4; ++q) {
      u16x8 v = *(const u16x8*)(src + q * 8);
#pragma unroll
      for (int i = 0; i < 8; ++i) kv[q * 8 + i] = b2f(v[i]);
    }
  }
  __syncthreads();
  float sum = 0.f;
  for (int nn = 0; nn < 128; ++nn) {
    float s = 0.f;
#pragma unroll
    for (int c = 0; c < 32; ++c) s += Qsf[nn][c] * kv[c];
    sum += __expf(fminf(s, 60.f));
  }
  psum[((size_t)(b * SEGS + seg)) * NN + m] = sum;
}

__global__ void k_rsum(const float* __restrict__ psum, float* __restrict__ rcs) {
  const int gid = blockIdx.x * 256 + threadIdx.x;  // B*N = 16384
  const int b = gid >> 12, m = gid & (NN - 1);
  float S = 0.f;
#pragma unroll
  for (int s = 0; s < SEGS; ++s) S += psum[((size_t)(b * SEGS + s)) * NN + m];
  rcs[gid] = 1.0f / S;
}

// ---------------------------------------------------------------------------
// MFMA main kernel. Output: bf16 fusion, channels-last padded fusb[b][66][66][256]
__global__ __launch_bounds__(512) void k_main(const unsigned short* __restrict__ Qt,
    const unsigned short* __restrict__ Kt, const unsigned short* __restrict__ Vb,
    const float* __restrict__ x, const float* __restrict__ rcs,
    const float* __restrict__ gamma, const float* __restrict__ spatial,
    unsigned short* __restrict__ fusb) {
  __shared__ unsigned short As[64 * 64];   // swizzled [n][m] bf16, 8 KB
  __shared__ unsigned short Fs[64][264];   // [n][c] staging, 33 KB
  const int b = blockIdx.y, n0 = blockIdx.x * 64;
  const int t = threadIdx.x;
  const int w = t >> 6, l = t & 63;
  const int lo = l & 15, hi = l >> 4;
  const int mt = w & 3, nt2 = w >> 2;      // S-phase tile assignment

  // Q fragments, kept in registers: [pos][batch]
  short8 qf[2][4];
#pragma unroll
  for (int pos = 0; pos < 2; ++pos) {
    const int n = n0 + (nt2 * 2 + pos) * 16 + lo;
#pragma unroll
    for (int bb = 0; bb < 4; ++bb)
      qf[pos][bb] = *(const short8*)(Qt + ((size_t)(bb * NN + n) * 32 + hi * 8));
  }

  f32x4 acc[2][4];
#pragma unroll
  for (int ct = 0; ct < 2; ++ct)
#pragma unroll
    for (int nt = 0; nt < 4; ++nt) acc[ct][nt] = (f32x4){0.f, 0.f, 0.f, 0.f};

  const float* rcs_b = rcs + b * NN;
  const f32x4 zero4 = (f32x4){0.f, 0.f, 0.f, 0.f};

  for (int m0 = 0; m0 < NN; m0 += 64) {
    const int mS = m0 + mt * 16 + lo;
    short8 kf[4];
#pragma unroll
    for (int bb = 0; bb < 4; ++bb)
      kf[bb] = *(const short8*)(Kt + ((size_t)(bb * NN + mS) * 32 + hi * 8));
    f32x4 s[2][4];
#pragma unroll
    for (int pos = 0; pos < 2; ++pos)
#pragma unroll
      for (int bb = 0; bb < 4; ++bb)
        s[pos][bb] = __builtin_amdgcn_mfma_f32_16x16x32_bf16(qf[pos][bb], kf[bb], zero4, 0, 0, 0);
    const float rcsm = rcs_b[mS];
    float av[2][4];
#pragma unroll
    for (int pos = 0; pos < 2; ++pos) {
#pragma unroll
      for (int r = 0; r < 4; ++r) {
        const float e0 = __expf(fminf(s[pos][0][r], 60.f));
        const float e1 = __expf(fminf(s[pos][1][r], 60.f));
        const float e2 = __expf(fminf(s[pos][2][r], 60.f));
        const float e3 = __expf(fminf(s[pos][3][r], 60.f));
        const float den = e0 + e1 + e2 + e3;
        const float eb = b == 0 ? e0 : (b == 1 ? e1 : (b == 2 ? e2 : e3));
        av[pos][r] = eb * (__builtin_amdgcn_rcpf(den) + rcsm);
      }
    }
    __syncthreads();
#pragma unroll
    for (int pos = 0; pos < 2; ++pos) {
      const int nl0 = (nt2 * 2 + pos) * 16 + hi * 4;
      const int ml = mt * 16 + lo;
#pragma unroll
      for (int r = 0; r < 4; ++r) {
        const int nl = nl0 + r;
        As[nl * 64 + (ml ^ ((nl & 7) << 3))] = f2b(av[pos][r]);
      }
    }
    __syncthreads();
#pragma unroll
    for (int kt = 0; kt < 2; ++kt) {
      short8 vf[2];
#pragma unroll
      for (int ct = 0; ct < 2; ++ct) {
        const int c = w * 32 + ct * 16 + lo;
        vf[ct] = *(const short8*)(Vb + ((size_t)(b * CC + c) * NN + m0 + kt * 32 + hi * 8));
      }
#pragma unroll
      for (int nt = 0; nt < 4; ++nt) {
        const int nl = nt * 16 + lo;
        const short8 af = *(const short8*)(As + nl * 64 + (((kt * 4 + hi) ^ (nl & 7)) << 3));
        acc[0][nt] = __builtin_amdgcn_mfma_f32_16x16x32_bf16(vf[0], af, acc[0][nt], 0, 0, 0);
        acc[1][nt] = __builtin_amdgcn_mfma_f32_16x16x32_bf16(vf[1], af, acc[1][nt], 0, 0, 0);
      }
    }
  }
  // ---- epilogue: bf16(g*acc + x) -> Fs[n][c] -> coalesced fusb writes
  const float g = gamma[0] * spatial[b];
#pragma unroll
  for (int ct = 0; ct < 2; ++ct) {
#pragma unroll
    for (int nt = 0; nt < 4; ++nt) {
      const int nl = nt * 16 + lo;
      const int cb = w * 32 + ct * 16 + hi * 4;
      u16x4 o4;
#pragma unroll
      for (int r = 0; r < 4; ++r) {
        const size_t off = ((size_t)(b * CC + cb + r)) * NN + n0 + nl;
        o4[r] = f2b(g * acc[ct][nt][r] + x[off]);
      }
      *(u16x4*)&Fs[nl][cb] = o4;
    }
  }
  __syncthreads();
  const int iy = blockIdx.x;  // n0 >> 6
  const size_t pbase = ((size_t)(b * 66 + iy + 1)) * 66 + 1;
#pragma unroll
  for (int q = 0; q < 4; ++q) {
    const int flat = t + q * 512;          // 0..2047
    const int nl = flat >> 5, c0 = (flat & 31) * 8;
    u16x8 v = *(const u16x8*)&Fs[nl][c0];
    *(u16x8*)(fusb + (pbase + nl) * 256 + c0) = v;
  }
}

// ---------------------------------------------------------------------------
// weight transform: wbf[p][tap][o][ic] (bf16, ic contiguous)
__global__ void k_wprep(const float* __restrict__ w_co, unsigned short* __restrict__ wbf) {
  const int gid = blockIdx.x * 256 + threadIdx.x;  // 4*4*128*256 = 524288
  const int ic = gid & 255;
  const int o = (gid >> 8) & 127;
  const int tap = (gid >> 15) & 3;
  const int p = gid >> 17;
  const int py = p >> 1, px = p & 1;
  const int tyi = tap >> 1, txi = tap & 1;
  const int ky = py + 2 * tyi, kx = px + 2 * txi;
  wbf[gid] = f2b(w_co[(ic * 128 + o) * 16 + (3 - ky) * 4 + (3 - kx)]);
}

// ---------------------------------------------------------------------------
// MFMA transposed conv: per (b,parity): out[o][n] = sum_{tap,ic} W[tap][o][ic]*F[ic][n+shift]
// grid (16 row-groups, 16 b*4+p), 512 thr = 8 waves: wave = (row, oc-half)
__global__ __launch_bounds__(512) void k_deconv(const unsigned short* __restrict__ fusb,
    const unsigned short* __restrict__ wbf, const float* __restrict__ b_co,
    float* __restrict__ out) {
  const int bp = blockIdx.y;               // b*4 + py*2 + px
  const int b = bp >> 2, py = (bp >> 1) & 1, px = bp & 1;
  const int t = threadIdx.x;
  const int w = t >> 6, l = t & 63;
  const int lo = l & 15, hi = l >> 4;
  const int wm = w & 1, wrow = w >> 1;
  const int iy = blockIdx.x * 4 + wrow;    // input spatial row 0..63
  f32x4 acc[4][4];
#pragma unroll
  for (int mt = 0; mt < 4; ++mt)
#pragma unroll
    for (int nt = 0; nt < 4; ++nt) acc[mt][nt] = (f32x4){0.f, 0.f, 0.f, 0.f};
  const unsigned short* wp_base = wbf + (size_t)(bp & 3) * 4 * 128 * 256;
  for (int tap = 0; tap < 4; ++tap) {
    const int tyi = tap >> 1, txi = tap & 1;
    const int dy = py + tyi - 1, dx = px + txi - 1;
    const unsigned short* wtap = wp_base + (size_t)tap * 128 * 256 + (size_t)(wm * 64 + lo) * 256 + hi * 8;
    const unsigned short* fb = fusb + ((size_t)(b * 66 + iy + dy + 1) * 66 + (lo + dx + 1)) * 256 + hi * 8;
#pragma unroll
    for (int ic0 = 0; ic0 < 256; ic0 += 32) {
      short8 a[4], bf[4];
#pragma unroll
      for (int mt = 0; mt < 4; ++mt) a[mt] = *(const short8*)(wtap + mt * 16 * 256 + ic0);
#pragma unroll
      for (int nt = 0; nt < 4; ++nt) bf[nt] = *(const short8*)(fb + nt * 16 * 256 + ic0);
#pragma unroll
      for (int mt = 0; mt < 4; ++mt)
#pragma unroll
        for (int nt = 0; nt < 4; ++nt)
          acc[mt][nt] = __builtin_amdgcn_mfma_f32_16x16x32_bf16(a[mt], bf[nt], acc[mt][nt], 0, 0, 0);
    }
  }
  const int y = 2 * iy + py;
#pragma unroll
  for (int mt = 0; mt < 4; ++mt) {
#pragma unroll
    for (int nt = 0; nt < 4; ++nt) {
#pragma unroll
      for (int r = 0; r < 4; ++r) {
        const int o = wm * 64 + mt * 16 + hi * 4 + r;
        const int xx = 2 * (nt * 16 + lo) + px;
        out[(((size_t)(b * OCH + o)) * 128 + y) * 128 + xx] = acc[mt][nt][r] + b_co[o];
      }
    }
  }
}

// ---------------------------------------------------------------------------
extern "C" void kernel_launch(void* const* d_in, const int* in_sizes, int n_in,
                              void* d_out, int out_size, void* d_ws, size_t ws_size,
                              hipStream_t stream) {
  const float* x     = (const float*)d_in[0];
  const float* wq    = (const float*)d_in[1];
  const float* bq    = (const float*)d_in[2];
  const float* wv    = (const float*)d_in[3];
  const float* bv    = (const float*)d_in[4];
  const float* w1    = (const float*)d_in[5];
  const float* b1    = (const float*)d_in[6];
  const float* w2    = (const float*)d_in[7];
  const float* b2    = (const float*)d_in[8];
  const float* gamma = (const float*)d_in[9];
  const float* w_co  = (const float*)d_in[10];
  const float* b_co  = (const float*)d_in[11];
  float* out = (float*)d_out;

  char* p = (char*)d_ws;
  float*          q1      = (float*)p;          p += (size_t)4194304 * 4;  // 16.8 MB
  unsigned short* Vb      = (unsigned short*)p; p += (size_t)4194304 * 2;  // 8.4 MB
  float*          q2      = (float*)p;          p += (size_t)524288 * 4;   // 2 MB
  unsigned short* Qt      = (unsigned short*)p; p += (size_t)524288 * 2;   // 1 MB
  unsigned short* Kt      = (unsigned short*)p; p += (size_t)524288 * 2;   // 1 MB
  float*          psum    = (float*)p;          p += (size_t)524288 * 4;   // 2 MB
  float*          rcs     = (float*)p;          p += (size_t)16384 * 4;
  float*          part    = (float*)p;          p += (size_t)256 * 4;
  float*          spatial = (float*)p;          p += (size_t)4 * 16;
  unsigned short* wbf     = (unsigned short*)p; p += (size_t)524288 * 2;   // 1 MB
  unsigned short* fusb    = (unsigned short*)p;                            // 8.9 MB
  (void)ws_size; (void)in_sizes; (void)n_in; (void)out_size;

  // zero the padded fusion buffer (borders must be 0 for shifted deconv reads)
  hipMemsetAsync(fusb, 0, (size_t)4 * 66 * 66 * 256 * 2, stream);

  k_proj<<<dim3(64, 4, 4), 256, 0, stream>>>(x, wq, bq, q1);
  k_projb<<<dim3(64, 4, 4), 256, 0, stream>>>(x, wv, bv, Vb);
  k_adj1<<<dim3(2048), 256, 0, stream>>>(q1, w1, b1, q2);
  k_adj2<<<dim3(64, 4), 256, 0, stream>>>(q2, w2, b2, Qt, Kt);
  k_spatial1<<<dim3(64, 4), 256, 0, stream>>>(x, part);
  k_spatial2<<<dim3(1), 256, 0, stream>>>(part, spatial);
  k_colstat<<<dim3(16, SEGS, 4), 256, 0, stream>>>(Qt, Kt, psum);
  k_rsum<<<dim3(64), 256, 0, stream>>>(psum, rcs);
  k_main<<<dim3(64, 4), 512, 0, stream>>>(Qt, Kt, Vb, x, rcs, gamma, spatial, fusb);
  k_wprep<<<dim3(2048), 256, 0, stream>>>(w_co, wbf);
  k_deconv<<<dim3(16, 16), 512, 0, stream>>>(fusb, wbf, b_co, out);
}

// Round 4
// 377.692 us; speedup vs baseline: 7.8293x; 1.2125x over previous
//
#include <hip/hip_runtime.h>

#define BN 4
#define CC 256
#define NN 4096
#define CR 32
#define OCH 128
#define SEGS 8

typedef float f32x4 __attribute__((ext_vector_type(4)));
typedef short short8 __attribute__((ext_vector_type(8)));
typedef unsigned short u16x8 __attribute__((ext_vector_type(8)));
typedef unsigned short u16x4 __attribute__((ext_vector_type(4)));

__device__ __forceinline__ unsigned short f2b(float f) {
  unsigned u = __builtin_bit_cast(unsigned, f);
  u += 0x7fff + ((u >> 16) & 1);
  return (unsigned short)(u >> 16);
}
__device__ __forceinline__ float b2f(unsigned short h) {
  unsigned u = ((unsigned)h) << 16;
  return __builtin_bit_cast(float, u);
}

// ---------------------------------------------------------------------------
// cast wq / wv to bf16
__global__ __launch_bounds__(256) void k_wcast(const float* __restrict__ wq,
    const float* __restrict__ wv, unsigned short* __restrict__ wqb,
    unsigned short* __restrict__ wvb) {
  const int gid = (blockIdx.x * 256 + threadIdx.x) * 4;
  const float* src = blockIdx.y ? wv : wq;
  unsigned short* dst = blockIdx.y ? wvb : wqb;
  const float4 v = *(const float4*)(src + gid);
  u16x4 o; o[0] = f2b(v.x); o[1] = f2b(v.y); o[2] = f2b(v.z); o[3] = f2b(v.w);
  *(u16x4*)(dst + gid) = o;
}

// ---------------------------------------------------------------------------
// transpose+cast: x[b][c][n] f32 -> xt[b][n][c] bf16
__global__ __launch_bounds__(256) void k_xt(const float* __restrict__ x,
    unsigned short* __restrict__ xt) {
  __shared__ unsigned short T[64][65];
  const int b = blockIdx.z, c0 = blockIdx.y * 64, n0 = blockIdx.x * 64;
  const int t = threadIdx.x;
  for (int idx = t; idx < 4096; idx += 256) {
    int i = idx >> 6, j = idx & 63;
    T[i][j] = f2b(x[((size_t)(b * CC + c0 + i)) * NN + n0 + j]);
  }
  __syncthreads();
  for (int idx = t; idx < 4096; idx += 256) {
    int j = idx >> 6, i = idx & 63;
    xt[((size_t)(b * NN + n0 + j)) * CC + c0 + i] = T[i][j];
  }
}

// ---------------------------------------------------------------------------
// MFMA projection GEMM: out[b][c][n] = bias[c] + sum_j W[c][j] xt[b][n][j]
// z=0 -> (wqb,bq)->q1b ; z=1 -> (wvb,bv)->Vb.  bf16 out, [b][c][n] n-contig.
__global__ __launch_bounds__(256) void k_projm(const unsigned short* __restrict__ xt,
    const unsigned short* __restrict__ wqb, const float* __restrict__ bq,
    const unsigned short* __restrict__ wvb, const float* __restrict__ bv,
    unsigned short* __restrict__ q1b, unsigned short* __restrict__ Vb) {
  const int b = blockIdx.y, n0 = blockIdx.x * 32, which = blockIdx.z;
  const unsigned short* W = which ? wvb : wqb;
  const float* bias = which ? bv : bq;
  unsigned short* out = which ? Vb : q1b;
  const int t = threadIdx.x;
  const int w = t >> 6, l = t & 63;
  const int lo = l & 15, hi = l >> 4;
  const int oc0 = w * 64;
  f32x4 acc[4][2];
#pragma unroll
  for (int ct = 0; ct < 4; ++ct)
#pragma unroll
    for (int nt = 0; nt < 2; ++nt) acc[ct][nt] = (f32x4){0.f, 0.f, 0.f, 0.f};
  const unsigned short* wb = W + (size_t)(oc0 + lo) * CC + hi * 8;
  const unsigned short* xb = xt + ((size_t)(b * NN + n0 + lo)) * CC + hi * 8;
#pragma unroll
  for (int k0 = 0; k0 < CC; k0 += 32) {
    short8 aw[4], bx[2];
#pragma unroll
    for (int ct = 0; ct < 4; ++ct) aw[ct] = *(const short8*)(wb + ct * 16 * CC + k0);
#pragma unroll
    for (int nt = 0; nt < 2; ++nt) bx[nt] = *(const short8*)(xb + nt * 16 * CC + k0);
#pragma unroll
    for (int ct = 0; ct < 4; ++ct)
#pragma unroll
      for (int nt = 0; nt < 2; ++nt)
        acc[ct][nt] = __builtin_amdgcn_mfma_f32_16x16x32_bf16(aw[ct], bx[nt], acc[ct][nt], 0, 0, 0);
  }
#pragma unroll
  for (int ct = 0; ct < 4; ++ct) {
#pragma unroll
    for (int r = 0; r < 4; ++r) {
      const int c = oc0 + ct * 16 + hi * 4 + r;
      const float bvv = bias[c];
#pragma unroll
      for (int nt = 0; nt < 2; ++nt)
        out[((size_t)(b * CC + c)) * NN + n0 + nt * 16 + lo] = f2b(acc[ct][nt][r] + bvv);
    }
  }
}

// ---------------------------------------------------------------------------
// grouped conv1d (bf16 in, f32 out)
__global__ __launch_bounds__(256) void k_adj1(const unsigned short* __restrict__ q1,
    const float* __restrict__ w1, const float* __restrict__ b1,
    float* __restrict__ q2) {
  const int gid = blockIdx.x * 256 + threadIdx.x;  // B*32*N
  const int n = gid & (NN - 1);
  const int o = (gid >> 12) & 31;
  const int b = gid >> 17;
  const unsigned short* base = q1 + ((size_t)b * CC + o * 8) * NN;
  float s = b1[o];
#pragma unroll
  for (int i = 0; i < 8; ++i) {
    const unsigned short* r = base + (size_t)i * NN;
    const float wa = w1[o * 24 + i * 3 + 0];
    const float wb = w1[o * 24 + i * 3 + 1];
    const float wc = w1[o * 24 + i * 3 + 2];
    if (n > 0) s += wa * b2f(r[n - 1]);
    s += wb * b2f(r[n]);
    if (n < NN - 1) s += wc * b2f(r[n + 1]);
  }
  q2[((size_t)b * CR + o) * NN + n] = s;
}

// ---------------------------------------------------------------------------
// conv1d 32->64ch, writes bf16 TRANSPOSED Qt[b][n][32], Kt[b][n][32]
__global__ __launch_bounds__(256) void k_adj2(const float* __restrict__ q2,
    const float* __restrict__ w2, const float* __restrict__ b2,
    unsigned short* __restrict__ Qt, unsigned short* __restrict__ Kt) {
  __shared__ float q2s[32][66];
  __shared__ float w2t[96][64];
  __shared__ float b2s[64];
  const int b = blockIdx.y, n0 = blockIdx.x * 64;
  const int t = threadIdx.x;
  for (int idx = t; idx < 32 * 66; idx += 256) {
    int c = idx / 66, nn = idx % 66;
    int n = n0 + nn - 1;
    q2s[c][nn] = (n >= 0 && n < NN) ? q2[((size_t)b * CR + c) * NN + n] : 0.f;
  }
  for (int idx = t; idx < 96 * 64; idx += 256) {
    int k = idx & 63, ct = idx >> 6;
    w2t[ct][k] = w2[k * 96 + ct];
  }
  if (t < 64) b2s[t] = b2[t];
  __syncthreads();
  const int nn = t & 63, kh = t >> 6;
  float acc[16];
#pragma unroll
  for (int i = 0; i < 16; ++i) acc[i] = b2s[kh * 16 + i];
  for (int c = 0; c < 32; ++c) {
    const float x0 = q2s[c][nn], x1 = q2s[c][nn + 1], x2 = q2s[c][nn + 2];
    const float* wa = &w2t[c * 3 + 0][kh * 16];
    const float* wb = &w2t[c * 3 + 1][kh * 16];
    const float* wc = &w2t[c * 3 + 2][kh * 16];
#pragma unroll
    for (int i = 0; i < 16; ++i)
      acc[i] += wa[i] * x0 + wb[i] * x1 + wc[i] * x2;
  }
  const size_t row = ((size_t)b * NN + n0 + nn) * 32;
  u16x8 qo, ko;
#pragma unroll
  for (int i = 0; i < 8; ++i) {
    qo[i] = f2b(acc[2 * i]);
    ko[i] = f2b(acc[2 * i + 1]);
  }
  *(u16x8*)(Qt + row + kh * 8) = qo;
  *(u16x8*)(Kt + row + kh * 8) = ko;
}

// ---------------------------------------------------------------------------
// spatial mean of x per batch
__global__ __launch_bounds__(256) void k_spatial1(const float* __restrict__ x,
                                                  float* __restrict__ part) {
  const int b = blockIdx.y;
  const size_t off = (size_t)b * CC * NN + (size_t)blockIdx.x * 16384;
  float s = 0.f;
  for (int i = threadIdx.x; i < 16384; i += 256) s += x[off + i];
  __shared__ float red[256];
  red[threadIdx.x] = s;
  __syncthreads();
  for (int d = 128; d > 0; d >>= 1) {
    if (threadIdx.x < d) red[threadIdx.x] += red[threadIdx.x + d];
    __syncthreads();
  }
  if (threadIdx.x == 0) part[b * 64 + blockIdx.x] = red[0];
}

__global__ void k_spatial2(const float* __restrict__ part, float* __restrict__ spatial) {
  const int t = threadIdx.x;
  const int b = t >> 6, i = t & 63;
  float s = part[b * 64 + i];
  for (int d = 32; d > 0; d >>= 1) s += __shfl_down(s, d, 64);
  if (i == 0) spatial[b] = s * (1.0f / ((float)CC * NN));
}

// ---------------------------------------------------------------------------
// MFMA column exp-sum: psum[b][seg][m] = sum_{n in seg} exp(S[b][n][m])
// grid (64 m-tiles, 8 n-segs), 512 thr = 8 waves (mt=w&3, nt2=w>>2)
__global__ __launch_bounds__(512) void k_colstatm(const unsigned short* __restrict__ Qt,
    const unsigned short* __restrict__ Kt, float* __restrict__ psum) {
  __shared__ float CS[2][4][64];
  const int m0 = blockIdx.x * 64, seg = blockIdx.y;
  const int t = threadIdx.x;
  const int w = t >> 6, l = t & 63;
  const int lo = l & 15, hi = l >> 4;
  const int mt = w & 3, nt2 = w >> 2;
  const f32x4 zero4 = (f32x4){0.f, 0.f, 0.f, 0.f};
  short8 kf[4];
#pragma unroll
  for (int bb = 0; bb < 4; ++bb)
    kf[bb] = *(const short8*)(Kt + ((size_t)(bb * NN + m0 + mt * 16 + lo)) * 32 + hi * 8);
  float colacc[4] = {0.f, 0.f, 0.f, 0.f};
  for (int ch = 0; ch < 8; ++ch) {
    const int nb = seg * 512 + ch * 64;
    short8 qf[2][4];
#pragma unroll
    for (int pos = 0; pos < 2; ++pos)
#pragma unroll
      for (int bb = 0; bb < 4; ++bb)
        qf[pos][bb] = *(const short8*)(Qt + ((size_t)(bb * NN + nb + (nt2 * 2 + pos) * 16 + lo)) * 32 + hi * 8);
#pragma unroll
    for (int pos = 0; pos < 2; ++pos) {
#pragma unroll
      for (int bb = 0; bb < 4; ++bb) {
        const f32x4 s = __builtin_amdgcn_mfma_f32_16x16x32_bf16(qf[pos][bb], kf[bb], zero4, 0, 0, 0);
#pragma unroll
        for (int r = 0; r < 4; ++r) colacc[bb] += __expf(fminf(s[r], 60.f));
      }
    }
  }
#pragma unroll
  for (int bb = 0; bb < 4; ++bb) {
    colacc[bb] += __shfl_xor(colacc[bb], 16, 64);
    colacc[bb] += __shfl_xor(colacc[bb], 32, 64);
  }
  if (hi == 0) {
#pragma unroll
    for (int bb = 0; bb < 4; ++bb) CS[nt2][bb][mt * 16 + lo] = colacc[bb];
  }
  __syncthreads();
  if (t < 256) {
    const int bb = t >> 6, mm = t & 63;
    psum[((size_t)(bb * SEGS + seg)) * NN + m0 + mm] = CS[0][bb][mm] + CS[1][bb][mm];
  }
}

__global__ void k_rsum(const float* __restrict__ psum, float* __restrict__ rcs) {
  const int gid = blockIdx.x * 256 + threadIdx.x;  // B*N = 16384
  const int b = gid >> 12, m = gid & (NN - 1);
  float S = 0.f;
#pragma unroll
  for (int s = 0; s < SEGS; ++s) S += psum[((size_t)(b * SEGS + s)) * NN + m];
  rcs[gid] = 1.0f / S;
}

// ---------------------------------------------------------------------------
// A-generation: S via MFMA (once per (n,m)), double softmax, write A bf16
// A local layout: [4][stripeN][NN] m-contig.  grid (stripeN/64, 8 m-segs), 512 thr.
__global__ __launch_bounds__(512) void k_agen(const unsigned short* __restrict__ Qt,
    const unsigned short* __restrict__ Kt, const float* __restrict__ rcs,
    unsigned short* __restrict__ A, int n_base, int stripeN) {
  __shared__ unsigned short As[4][64][72];
  const int n0 = n_base + blockIdx.x * 64, mseg = blockIdx.y;
  const int t = threadIdx.x;
  const int w = t >> 6, l = t & 63;
  const int lo = l & 15, hi = l >> 4;
  const int mt = w & 3, nt2 = w >> 2;
  const f32x4 zero4 = (f32x4){0.f, 0.f, 0.f, 0.f};
  short8 qf[2][4];
#pragma unroll
  for (int pos = 0; pos < 2; ++pos)
#pragma unroll
    for (int bb = 0; bb < 4; ++bb)
      qf[pos][bb] = *(const short8*)(Qt + ((size_t)(bb * NN + n0 + (nt2 * 2 + pos) * 16 + lo)) * 32 + hi * 8);
  for (int ch = 0; ch < 8; ++ch) {
    const int m0 = mseg * 512 + ch * 64;
    const int mS = m0 + mt * 16 + lo;
    short8 kf[4];
#pragma unroll
    for (int bb = 0; bb < 4; ++bb)
      kf[bb] = *(const short8*)(Kt + ((size_t)(bb * NN + mS)) * 32 + hi * 8);
    f32x4 s[2][4];
#pragma unroll
    for (int pos = 0; pos < 2; ++pos)
#pragma unroll
      for (int bb = 0; bb < 4; ++bb)
        s[pos][bb] = __builtin_amdgcn_mfma_f32_16x16x32_bf16(qf[pos][bb], kf[bb], zero4, 0, 0, 0);
    float rc[4];
#pragma unroll
    for (int bb = 0; bb < 4; ++bb) rc[bb] = rcs[bb * NN + mS];
    unsigned short av[2][4][4];
#pragma unroll
    for (int pos = 0; pos < 2; ++pos) {
#pragma unroll
      for (int r = 0; r < 4; ++r) {
        float e[4];
#pragma unroll
        for (int bb = 0; bb < 4; ++bb) e[bb] = __expf(fminf(s[pos][bb][r], 60.f));
        const float rden = __builtin_amdgcn_rcpf(e[0] + e[1] + e[2] + e[3]);
#pragma unroll
        for (int bb = 0; bb < 4; ++bb) av[pos][r][bb] = f2b(e[bb] * (rden + rc[bb]));
      }
    }
    __syncthreads();   // previous copy-out done
#pragma unroll
    for (int pos = 0; pos < 2; ++pos) {
      const int nl0 = (nt2 * 2 + pos) * 16 + hi * 4;
      const int ml = mt * 16 + lo;
#pragma unroll
      for (int r = 0; r < 4; ++r)
#pragma unroll
        for (int bb = 0; bb < 4; ++bb) As[bb][nl0 + r][ml] = av[pos][r][bb];
    }
    __syncthreads();
    // coalesced copy-out: 2048 u16x8 units
#pragma unroll
    for (int q = 0; q < 4; ++q) {
      const int u = t + q * 512;
      const int bb = u >> 9, rest = u & 511;
      const int nl = rest >> 3, mg = (rest & 7) * 8;
      u16x8 v = *(const u16x8*)&As[bb][nl][mg];
      *(u16x8*)(A + ((size_t)bb * stripeN + (n0 - n_base) + nl) * NN + m0 + mg) = v;
    }
  }
}

// ---------------------------------------------------------------------------
// PV GEMM + epilogue: fus[b][c][n] = g*sum_m V[c][m]*A[n][m] + x -> bf16 fusb
// grid (stripeN/64, 4 b), 512 thr = 8 waves (cg=w&3, nh=w>>2)
__global__ __launch_bounds__(512) void k_pv(const unsigned short* __restrict__ Vb,
    const unsigned short* __restrict__ A, const float* __restrict__ x,
    const float* __restrict__ gamma, const float* __restrict__ spatial,
    unsigned short* __restrict__ fusb, int n_base, int stripeN) {
  __shared__ unsigned short Fs[64][264];
  const int b = blockIdx.y;
  const int nloc0 = blockIdx.x * 64;
  const int t = threadIdx.x;
  const int w = t >> 6, l = t & 63;
  const int lo = l & 15, hi = l >> 4;
  const int cg = w & 3, nh = w >> 2;
  f32x4 acc[4][2];
#pragma unroll
  for (int ct = 0; ct < 4; ++ct)
#pragma unroll
    for (int nt = 0; nt < 2; ++nt) acc[ct][nt] = (f32x4){0.f, 0.f, 0.f, 0.f};
  const unsigned short* vb = Vb + ((size_t)(b * CC + cg * 64 + lo)) * NN + hi * 8;
  const unsigned short* ab = A + ((size_t)b * stripeN + nloc0 + nh * 32 + lo) * NN + hi * 8;
#pragma unroll 4
  for (int m0 = 0; m0 < NN; m0 += 32) {
    short8 vf[4], af[2];
#pragma unroll
    for (int ct = 0; ct < 4; ++ct) vf[ct] = *(const short8*)(vb + (size_t)ct * 16 * NN + m0);
#pragma unroll
    for (int nt = 0; nt < 2; ++nt) af[nt] = *(const short8*)(ab + (size_t)nt * 16 * NN + m0);
#pragma unroll
    for (int ct = 0; ct < 4; ++ct)
#pragma unroll
      for (int nt = 0; nt < 2; ++nt)
        acc[ct][nt] = __builtin_amdgcn_mfma_f32_16x16x32_bf16(vf[ct], af[nt], acc[ct][nt], 0, 0, 0);
  }
  // epilogue into LDS then coalesced channels-last store
  const float g = gamma[0] * spatial[b];
  const int n_abs0 = n_base + nloc0;
#pragma unroll
  for (int ct = 0; ct < 4; ++ct) {
#pragma unroll
    for (int r = 0; r < 4; ++r) {
      const int c = cg * 64 + ct * 16 + hi * 4 + r;
#pragma unroll
      for (int nt = 0; nt < 2; ++nt) {
        const int nl = nh * 32 + nt * 16 + lo;
        const float xv = x[((size_t)(b * CC + c)) * NN + n_abs0 + nl];
        Fs[nl][c] = f2b(g * acc[ct][nt][r] + xv);
      }
    }
  }
  __syncthreads();
  const int iy = (n_abs0) >> 6;   // 64-aligned
  const size_t pbase = ((size_t)(b * 66 + iy + 1)) * 66 + 1;
#pragma unroll
  for (int q = 0; q < 4; ++q) {
    const int flat = t + q * 512;          // 0..2047
    const int nl = flat >> 5, c0 = (flat & 31) * 8;
    u16x8 v = *(const u16x8*)&Fs[nl][c0];
    *(u16x8*)(fusb + (pbase + nl) * 256 + c0) = v;
  }
}

// ---------------------------------------------------------------------------
// weight transform: wbf[p][tap][o][ic] (bf16, ic contiguous)
__global__ void k_wprep(const float* __restrict__ w_co, unsigned short* __restrict__ wbf) {
  const int gid = blockIdx.x * 256 + threadIdx.x;
  const int ic = gid & 255;
  const int o = (gid >> 8) & 127;
  const int tap = (gid >> 15) & 3;
  const int p = gid >> 17;
  const int py = p >> 1, px = p & 1;
  const int tyi = tap >> 1, txi = tap & 1;
  const int ky = py + 2 * tyi, kx = px + 2 * txi;
  wbf[gid] = f2b(w_co[(ic * 128 + o) * 16 + (3 - ky) * 4 + (3 - kx)]);
}

// ---------------------------------------------------------------------------
// MFMA transposed conv
__global__ __launch_bounds__(512) void k_deconv(const unsigned short* __restrict__ fusb,
    const unsigned short* __restrict__ wbf, const float* __restrict__ b_co,
    float* __restrict__ out) {
  const int bp = blockIdx.y;
  const int b = bp >> 2, py = (bp >> 1) & 1, px = bp & 1;
  const int t = threadIdx.x;
  const int w = t >> 6, l = t & 63;
  const int lo = l & 15, hi = l >> 4;
  const int wm = w & 1, wrow = w >> 1;
  const int iy = blockIdx.x * 4 + wrow;
  f32x4 acc[4][4];
#pragma unroll
  for (int mt = 0; mt < 4; ++mt)
#pragma unroll
    for (int nt = 0; nt < 4; ++nt) acc[mt][nt] = (f32x4){0.f, 0.f, 0.f, 0.f};
  const unsigned short* wp_base = wbf + (size_t)(bp & 3) * 4 * 128 * 256;
  for (int tap = 0; tap < 4; ++tap) {
    const int tyi = tap >> 1, txi = tap & 1;
    const int dy = py + tyi - 1, dx = px + txi - 1;
    const unsigned short* wtap = wp_base + (size_t)tap * 128 * 256 + (size_t)(wm * 64 + lo) * 256 + hi * 8;
    const unsigned short* fb = fusb + ((size_t)(b * 66 + iy + dy + 1) * 66 + (lo + dx + 1)) * 256 + hi * 8;
#pragma unroll
    for (int ic0 = 0; ic0 < 256; ic0 += 32) {
      short8 a[4], bf[4];
#pragma unroll
      for (int mt = 0; mt < 4; ++mt) a[mt] = *(const short8*)(wtap + mt * 16 * 256 + ic0);
#pragma unroll
      for (int nt = 0; nt < 4; ++nt) bf[nt] = *(const short8*)(fb + nt * 16 * 256 + ic0);
#pragma unroll
      for (int mt = 0; mt < 4; ++mt)
#pragma unroll
        for (int nt = 0; nt < 4; ++nt)
          acc[mt][nt] = __builtin_amdgcn_mfma_f32_16x16x32_bf16(a[mt], bf[nt], acc[mt][nt], 0, 0, 0);
    }
  }
  const int y = 2 * iy + py;
#pragma unroll
  for (int mt = 0; mt < 4; ++mt) {
#pragma unroll
    for (int nt = 0; nt < 4; ++nt) {
#pragma unroll
      for (int r = 0; r < 4; ++r) {
        const int o = wm * 64 + mt * 16 + hi * 4 + r;
        const int xx = 2 * (nt * 16 + lo) + px;
        out[(((size_t)(b * OCH + o)) * 128 + y) * 128 + xx] = acc[mt][nt][r] + b_co[o];
      }
    }
  }
}

// ---------------------------------------------------------------------------
extern "C" void kernel_launch(void* const* d_in, const int* in_sizes, int n_in,
                              void* d_out, int out_size, void* d_ws, size_t ws_size,
                              hipStream_t stream) {
  const float* x     = (const float*)d_in[0];
  const float* wq    = (const float*)d_in[1];
  const float* bq    = (const float*)d_in[2];
  const float* wv    = (const float*)d_in[3];
  const float* bv    = (const float*)d_in[4];
  const float* w1    = (const float*)d_in[5];
  const float* b1    = (const float*)d_in[6];
  const float* w2    = (const float*)d_in[7];
  const float* b2    = (const float*)d_in[8];
  const float* gamma = (const float*)d_in[9];
  const float* w_co  = (const float*)d_in[10];
  const float* b_co  = (const float*)d_in[11];
  float* out = (float*)d_out;
  (void)in_sizes; (void)n_in; (void)out_size;

  // --- survivor region sizes (bytes) ---
  const size_t SZ_QT   = (size_t)BN * NN * 32 * 2;        // 1 MB
  const size_t SZ_VB   = (size_t)BN * CC * NN * 2;        // 8.4 MB
  const size_t SZ_RCS  = (size_t)BN * NN * 4;
  const size_t SZ_W    = (size_t)CC * CC * 2;             // 128 KB
  const size_t SZ_WBF  = (size_t)4 * 4 * 128 * 256 * 2;   // 1 MB
  const size_t SZ_FUSB = (size_t)BN * 66 * 66 * 256 * 2;  // 8.9 MB
  const size_t SURV = SZ_QT * 2 + SZ_VB + SZ_RCS + 256 + SZ_W * 2 + SZ_WBF + SZ_FUSB + 4096;

  // region0 holds early-dead temps, later overwritten by A
  const size_t SZ_XT  = (size_t)BN * NN * CC * 2;   // 8.4 MB
  const size_t SZ_Q1  = (size_t)BN * CC * NN * 2;   // 8.4 MB
  const size_t SZ_Q2  = (size_t)BN * CR * NN * 4;   // 2 MB
  const size_t SZ_PS  = (size_t)BN * SEGS * NN * 4; // 0.5 MB
  const size_t TEMPS  = SZ_XT + SZ_Q1 + SZ_Q2 + SZ_PS + 2048;

  int stripes;
  size_t a_bytes_full = (size_t)BN * NN * NN * 2;   // 134 MB
  if (ws_size >= a_bytes_full + SURV + (1 << 20)) stripes = 1;
  else if (ws_size >= a_bytes_full / 4 + SURV + (1 << 20) && a_bytes_full / 4 >= TEMPS) stripes = 4;
  else stripes = 8;
  const int stripeN = NN / stripes;
  const size_t R0 = (((size_t)BN * stripeN * NN * 2 > TEMPS) ? (size_t)BN * stripeN * NN * 2 : TEMPS);

  char* p0 = (char*)d_ws;
  unsigned short* A    = (unsigned short*)p0;
  unsigned short* xt   = (unsigned short*)p0;
  unsigned short* q1b  = (unsigned short*)(p0 + SZ_XT);
  float*          q2   = (float*)(p0 + SZ_XT + SZ_Q1);
  float*          psum = (float*)(p0 + SZ_XT + SZ_Q1 + SZ_Q2);
  float*          part = (float*)(p0 + SZ_XT + SZ_Q1 + SZ_Q2 + SZ_PS);

  char* ps = p0 + R0;
  unsigned short* Qt      = (unsigned short*)ps;            ps += SZ_QT;
  unsigned short* Kt      = (unsigned short*)ps;            ps += SZ_QT;
  unsigned short* Vb      = (unsigned short*)ps;            ps += SZ_VB;
  float*          rcs     = (float*)ps;                     ps += SZ_RCS;
  float*          spatial = (float*)ps;                     ps += 256;
  unsigned short* wqb     = (unsigned short*)ps;            ps += SZ_W;
  unsigned short* wvb     = (unsigned short*)ps;            ps += SZ_W;
  unsigned short* wbf     = (unsigned short*)ps;            ps += SZ_WBF;
  unsigned short* fusb    = (unsigned short*)ps;

  // border-zero padded fusion buffer
  hipMemsetAsync(fusb, 0, SZ_FUSB, stream);

  k_wcast<<<dim3(64, 2), 256, 0, stream>>>(wq, wv, wqb, wvb);
  k_xt<<<dim3(64, 4, 4), 256, 0, stream>>>(x, xt);
  k_projm<<<dim3(128, 4, 2), 256, 0, stream>>>(xt, wqb, bq, wvb, bv, q1b, Vb);
  k_adj1<<<dim3(2048), 256, 0, stream>>>(q1b, w1, b1, q2);
  k_adj2<<<dim3(64, 4), 256, 0, stream>>>(q2, w2, b2, Qt, Kt);
  k_spatial1<<<dim3(64, 4), 256, 0, stream>>>(x, part);
  k_spatial2<<<dim3(1), 256, 0, stream>>>(part, spatial);
  k_colstatm<<<dim3(64, SEGS), 512, 0, stream>>>(Qt, Kt, psum);
  k_rsum<<<dim3(64), 256, 0, stream>>>(psum, rcs);
  k_wprep<<<dim3(2048), 256, 0, stream>>>(w_co, wbf);
  for (int s = 0; s < stripes; ++s) {
    k_agen<<<dim3(stripeN / 64, 8), 512, 0, stream>>>(Qt, Kt, rcs, A, s * stripeN, stripeN);
    k_pv<<<dim3(stripeN / 64, 4), 512, 0, stream>>>(Vb, A, x, gamma, spatial, fusb, s * stripeN, stripeN);
  }
  k_deconv<<<dim3(16, 16), 512, 0, stream>>>(fusb, wbf, b_co, out);
}